// Round 1
// baseline (356.995 us; speedup 1.0000x reference)
//
#include <hip/hip_runtime.h>

// OverlapAdd: y[b,c,t] = sum_{k=0..3} x[b, k*128+c, t-k]  (t-k>=0)
// B=8, C_in=512, c_out=128, T=16000, fp32.
// Memory-bound: 262 MB read + 65.5 MB write -> ~52 us floor @ 6.3 TB/s.

#define OA_T4   4000                 // T/4 float4 per row
#define OA_N4   (1024 * OA_T4)       // (B*c_out) rows * T4

__global__ __launch_bounds__(256) void OverlapAdd_19490561590070_kernel(
    const float4* __restrict__ x, float4* __restrict__ y) {
    int i = blockIdx.x * 256 + threadIdx.x;
    if (i >= OA_N4) return;

    int row = i / OA_T4;             // row = b*128 + c, in [0,1024)
    int t4  = i - row * OA_T4;       // float4 index within the row
    int b   = row >> 7;
    int c   = row & 127;

    // input row base (in float4 units) for k=0; k strides by 128 rows
    const float4* p0 = x + ((long)(b * 512 + c)) * OA_T4 + t4;
    const float4* p1 = p0 + 128L * OA_T4;
    const float4* p2 = p0 + 256L * OA_T4;
    const float4* p3 = p0 + 384L * OA_T4;

    float4 B0 = *p0;
    float4 B1 = *p1;
    float4 B2 = *p2;
    float4 B3 = *p3;

    float4 A1, A2, A3;               // x_k[t-4 .. t-1]
    if (t4 > 0) {
        A1 = p1[-1];
        A2 = p2[-1];
        A3 = p3[-1];
    } else {                         // t==0: left-pad with zeros
        A1 = make_float4(0.f, 0.f, 0.f, 0.f);
        A2 = A1;
        A3 = A1;
    }

    // Same left-to-right add order as the reference: ((c0+s1)+s2)+s3
    float4 o;
    o.x = B0.x + A1.w + A2.z + A3.y;
    o.y = B0.y + B1.x + A2.w + A3.z;
    o.z = B0.z + B1.y + B2.x + A3.w;
    o.w = B0.w + B1.z + B2.y + B3.x;

    y[i] = o;
}

extern "C" void kernel_launch(void* const* d_in, const int* in_sizes, int n_in,
                              void* d_out, int out_size, void* d_ws, size_t ws_size,
                              hipStream_t stream) {
    const float4* x = (const float4*)d_in[0];
    float4*       y = (float4*)d_out;
    // OA_N4 = 4,096,000 threads = exactly 16000 blocks of 256
    OverlapAdd_19490561590070_kernel<<<dim3(OA_N4 / 256), dim3(256), 0, stream>>>(x, y);
}